// Round 2
// baseline (127.779 us; speedup 1.0000x reference)
//
#include <hip/hip_runtime.h>
#include <hip/hip_bf16.h>

// Batched matmul: [24,1024,64] fp32 x [24,64,1024] fp32 -> [24,1024,1024] fp32.
// Strategy: two tiny reformat kernels pack A and B into bf16 MFMA-fragment order
// in d_ws (6.3 MB), then an LDS-free/syncthreads-free MFMA kernel with fully
// coalesced dwordx4 fragment loads and float4 output stores (operand-swap gives
// C^T register layout -> 4 consecutive n per lane -> float4 stores).

#define NN 1024
#define KK 64

typedef __attribute__((ext_vector_type(4))) float  float4v;
typedef __attribute__((ext_vector_type(8))) short  bf16x8;    // 8 bf16 = 16 B
typedef __attribute__((ext_vector_type(16))) float floatx16;  // 32x32 MFMA acc

// fp32 -> bf16 bits, round-to-nearest-even (inputs finite)
__device__ __forceinline__ short f2bs(float f) {
    union { float f; unsigned u; } in;
    in.f = f;
    unsigned u = in.u;
    return (short)((u + 0x7FFFu + ((u >> 16) & 1u)) >> 16);
}

// Fragment layout (32x32x16 bf16, verified by R0 pass):
//   element (idx, k): tile = idx>>5, ks = k>>4, q = (k>>3)&1, j = k&7
//   lane = (idx&31) + q*32, short addr = ((bh*32+tile)*4 + ks)*512 + lane*8 + j
// A indexed by m over [m][k] row-major; B indexed by n over [k][n].

// ---- reformat A: task = [bh][m][kg], kg = k/8. Reads 32B contiguous per lane. ----
__global__ __launch_bounds__(256) void reformat_A(const float* __restrict__ A,
                                                  short* __restrict__ Aw) {
    int t0 = blockIdx.x * 256 + threadIdx.x;
    #pragma unroll
    for (int it = 0; it < 4; ++it) {
        int task = t0 + it * 49152;          // 0..196607
        int bh   = task >> 13;
        int rem  = task & 8191;
        int m    = rem >> 3;
        int kg   = rem & 7;
        const float4v* p = (const float4v*)(A + (size_t)task * 8);
        float4v v0 = p[0];
        float4v v1 = p[1];
        int ks = kg >> 1, q = kg & 1;
        int mt = m >> 5;
        int lane = (m & 31) + (q << 5);
        size_t dst = ((size_t)((bh * 32 + mt) * 4 + ks)) * 512 + (size_t)lane * 8;
        bf16x8 o;
        o[0] = f2bs(v0.x); o[1] = f2bs(v0.y); o[2] = f2bs(v0.z); o[3] = f2bs(v0.w);
        o[4] = f2bs(v1.x); o[5] = f2bs(v1.y); o[6] = f2bs(v1.z); o[7] = f2bs(v1.w);
        *(bf16x8*)(Aw + dst) = o;
    }
}

// ---- reformat B: task = [kg][bh][n] so lanes read 64 consecutive n (256B rows). ----
__global__ __launch_bounds__(256) void reformat_B(const float* __restrict__ B,
                                                  short* __restrict__ Bw) {
    int t0 = blockIdx.x * 256 + threadIdx.x;
    #pragma unroll
    for (int it = 0; it < 4; ++it) {
        int task = t0 + it * 49152;          // 0..196607
        int kg   = task / 24576;             // 0..7
        int rem  = task - kg * 24576;
        int bh   = rem >> 10;
        int n    = rem & 1023;
        const float* p = B + (size_t)bh * 65536 + (size_t)kg * 8192 + n;
        float v0 = p[0 * 1024], v1 = p[1 * 1024], v2 = p[2 * 1024], v3 = p[3 * 1024];
        float v4 = p[4 * 1024], v5 = p[5 * 1024], v6 = p[6 * 1024], v7 = p[7 * 1024];
        int ks = kg >> 1, q = kg & 1;
        int nt = n >> 5;
        int lane = (n & 31) + (q << 5);
        size_t dst = ((size_t)((bh * 32 + nt) * 4 + ks)) * 512 + (size_t)lane * 8;
        bf16x8 o;
        o[0] = f2bs(v0); o[1] = f2bs(v1); o[2] = f2bs(v2); o[3] = f2bs(v3);
        o[4] = f2bs(v4); o[5] = f2bs(v5); o[6] = f2bs(v6); o[7] = f2bs(v7);
        *(bf16x8*)(Bw + dst) = o;
    }
}

// ---- GEMM: no LDS, no syncthreads. Each wave: 64x64 output (2x2 of 32x32). ----
// Operand swap: acc = mfma(b_frag, a_frag, acc) computes D with
//   col = lane&31 -> m,  row = (r&3)+8*(r>>2)+4*(lane>>5) -> n
// so each lane holds 4 consecutive n per r-group -> float4 stores.
__global__ __launch_bounds__(256) void bmm_frag(const short* __restrict__ Aw,
                                                const short* __restrict__ Bw,
                                                float* __restrict__ C) {
    const int tid  = threadIdx.x;
    const int lane = tid & 63;
    const int w    = tid >> 6;
    const int bx = blockIdx.x;   // n-tile128 0..7
    const int by = blockIdx.y;   // m-tile128 0..7
    const int bh = blockIdx.z;   // 0..23
    const int wm = (w >> 1) * 2; // 32-tile base in m within the 128 tile
    const int wn = (w & 1) * 2;

    const short* Ab = Aw + ((size_t)((bh * 32 + by * 4 + wm) * 4)) * 512 + (size_t)lane * 8;
    const short* Bb = Bw + ((size_t)((bh * 32 + bx * 4 + wn) * 4)) * 512 + (size_t)lane * 8;
    // next 32-tile is +4*512 = +2048 shorts; next ks is +512 shorts

    floatx16 acc[2][2];
    #pragma unroll
    for (int mi = 0; mi < 2; ++mi)
        #pragma unroll
        for (int ni = 0; ni < 2; ++ni)
            #pragma unroll
            for (int r = 0; r < 16; ++r)
                acc[mi][ni][r] = 0.0f;

    #pragma unroll
    for (int ks = 0; ks < 4; ++ks) {
        bf16x8 a0 = *(const bf16x8*)(Ab + ks * 512);
        bf16x8 a1 = *(const bf16x8*)(Ab + 2048 + ks * 512);
        bf16x8 b0 = *(const bf16x8*)(Bb + ks * 512);
        bf16x8 b1 = *(const bf16x8*)(Bb + 2048 + ks * 512);
        acc[0][0] = __builtin_amdgcn_mfma_f32_32x32x16_bf16(b0, a0, acc[0][0], 0, 0, 0);
        acc[0][1] = __builtin_amdgcn_mfma_f32_32x32x16_bf16(b1, a0, acc[0][1], 0, 0, 0);
        acc[1][0] = __builtin_amdgcn_mfma_f32_32x32x16_bf16(b0, a1, acc[1][0], 0, 0, 0);
        acc[1][1] = __builtin_amdgcn_mfma_f32_32x32x16_bf16(b1, a1, acc[1][1], 0, 0, 0);
    }

    const int mc = lane & 31;          // m within 32-tile
    const int nb = (lane >> 5) * 4;    // n sub-base
    float* Cb = C + ((size_t)bh << 20)
                  + (size_t)(by * 128 + wm * 32 + mc) * NN
                  + bx * 128 + wn * 32 + nb;

    #pragma unroll
    for (int mi = 0; mi < 2; ++mi) {
        #pragma unroll
        for (int ni = 0; ni < 2; ++ni) {
            float* Ct = Cb + (size_t)(mi * 32) * NN + ni * 32;
            #pragma unroll
            for (int g = 0; g < 4; ++g) {
                float4v o;
                o.x = acc[mi][ni][4 * g + 0];
                o.y = acc[mi][ni][4 * g + 1];
                o.z = acc[mi][ni][4 * g + 2];
                o.w = acc[mi][ni][4 * g + 3];
                *(float4v*)(Ct + 8 * g) = o;
            }
        }
    }
}

extern "C" void kernel_launch(void* const* d_in, const int* in_sizes, int n_in,
                              void* d_out, int out_size, void* d_ws, size_t ws_size,
                              hipStream_t stream) {
    const float* x1 = (const float*)d_in[0];   // [2,12,1024,64]
    const float* x2 = (const float*)d_in[1];   // [2,12,64,1024]
    float* out = (float*)d_out;                // [2,12,1024,1024] fp32

    short* Aw = (short*)d_ws;                  // 1,572,864 bf16 = 3.1 MB
    short* Bw = Aw + 1572864;                  // 3.1 MB

    hipLaunchKernelGGL(reformat_A, dim3(192), dim3(256), 0, stream, x1, Aw);
    hipLaunchKernelGGL(reformat_B, dim3(192), dim3(256), 0, stream, x2, Bw);
    hipLaunchKernelGGL(bmm_frag, dim3(8, 8, 24), dim3(256), 0, stream, Aw, Bw, out);
}

// Round 3
// 123.322 us; speedup vs baseline: 1.0361x; 1.0361x over previous
//
#include <hip/hip_runtime.h>
#include <hip/hip_bf16.h>

// Batched matmul: [24,1024,64] fp32 x [24,64,1024] fp32 -> [24,1024,1024] fp32.
// R3: fused reformat kernel (A+B -> bf16 MFMA-fragment order in d_ws), then an
// LDS-free, barrier-free MFMA GEMM with NON-swapped operands so the C/D layout
// has n contiguous across lanes (col=lane&31 -> n): every scalar store instr
// covers 2 full 128-B lines. Stores are non-temporal (100 MB stream, don't
// allocate in L2).

#define NN 1024
#define KK 64

typedef __attribute__((ext_vector_type(4))) float  float4v;
typedef __attribute__((ext_vector_type(8))) short  bf16x8;    // 8 bf16 = 16 B
typedef __attribute__((ext_vector_type(16))) float floatx16;  // 32x32 MFMA acc

// fp32 -> bf16 bits, round-to-nearest-even (inputs finite)
__device__ __forceinline__ short f2bs(float f) {
    union { float f; unsigned u; } in;
    in.f = f;
    unsigned u = in.u;
    return (short)((u + 0x7FFFu + ((u >> 16) & 1u)) >> 16);
}

// Fragment layout (32x32x16 bf16; verified end-to-end in R1/R2 passes):
//   element (idx, k): tile = idx>>5, ks = k>>4, q = (k>>3)&1, j = k&7
//   lane = (idx&31) + q*32, short addr = ((bh*32+tile)*4 + ks)*512 + lane*8 + j
// A indexed by m over [m][k] row-major; B indexed by n over [k][n].

// Fused reformat: blocks 0..191 do A, blocks 192..383 do B.
__global__ __launch_bounds__(256) void reformat_AB(const float* __restrict__ A,
                                                   const float* __restrict__ B,
                                                   short* __restrict__ Aw,
                                                   short* __restrict__ Bw) {
    if (blockIdx.x < 192) {
        int t0 = blockIdx.x * 256 + threadIdx.x;
        #pragma unroll
        for (int it = 0; it < 4; ++it) {
            int task = t0 + it * 49152;          // 0..196607  [bh][m][kg]
            int bh   = task >> 13;
            int rem  = task & 8191;
            int m    = rem >> 3;
            int kg   = rem & 7;
            const float4v* p = (const float4v*)(A + (size_t)task * 8);
            float4v v0 = p[0];
            float4v v1 = p[1];
            int ks = kg >> 1, q = kg & 1;
            int mt = m >> 5;
            int lane = (m & 31) + (q << 5);
            size_t dst = ((size_t)((bh * 32 + mt) * 4 + ks)) * 512 + (size_t)lane * 8;
            bf16x8 o;
            o[0] = f2bs(v0.x); o[1] = f2bs(v0.y); o[2] = f2bs(v0.z); o[3] = f2bs(v0.w);
            o[4] = f2bs(v1.x); o[5] = f2bs(v1.y); o[6] = f2bs(v1.z); o[7] = f2bs(v1.w);
            *(bf16x8*)(Aw + dst) = o;
        }
    } else {
        int t0 = (blockIdx.x - 192) * 256 + threadIdx.x;
        #pragma unroll
        for (int it = 0; it < 4; ++it) {
            int task = t0 + it * 49152;          // 0..196607  [kg][bh][n]
            int kg   = task / 24576;             // 0..7
            int rem  = task - kg * 24576;
            int bh   = rem >> 10;
            int n    = rem & 1023;
            const float* p = B + (size_t)bh * 65536 + (size_t)kg * 8192 + n;
            float v0 = p[0 * 1024], v1 = p[1 * 1024], v2 = p[2 * 1024], v3 = p[3 * 1024];
            float v4 = p[4 * 1024], v5 = p[5 * 1024], v6 = p[6 * 1024], v7 = p[7 * 1024];
            int ks = kg >> 1, q = kg & 1;
            int nt = n >> 5;
            int lane = (n & 31) + (q << 5);
            size_t dst = ((size_t)((bh * 32 + nt) * 4 + ks)) * 512 + (size_t)lane * 8;
            bf16x8 o;
            o[0] = f2bs(v0); o[1] = f2bs(v1); o[2] = f2bs(v2); o[3] = f2bs(v3);
            o[4] = f2bs(v4); o[5] = f2bs(v5); o[6] = f2bs(v6); o[7] = f2bs(v7);
            *(bf16x8*)(Bw + dst) = o;
        }
    }
}

// GEMM: no LDS, no syncthreads. Each wave: 64x64 output (2x2 of 32x32).
// Non-swapped mfma(a,b,acc): col = lane&31 -> n (contiguous across lanes),
// row = (r&3)+8*(r>>2)+4*(lane>>5) -> m. Each scalar store instr covers
// exactly 2 full 128-B lines (rows r and r+4). Non-temporal stores.
__global__ __launch_bounds__(256) void bmm_frag(const short* __restrict__ Aw,
                                                const short* __restrict__ Bw,
                                                float* __restrict__ C) {
    const int tid  = threadIdx.x;
    const int lane = tid & 63;
    const int w    = tid >> 6;
    const int bx = blockIdx.x;   // n-tile128 0..7
    const int by = blockIdx.y;   // m-tile128 0..7
    const int bh = blockIdx.z;   // 0..23
    const int wm = (w >> 1) * 2; // 32-tile base in m within the 128 tile
    const int wn = (w & 1) * 2;

    const short* Ab = Aw + ((size_t)((bh * 32 + by * 4 + wm) * 4)) * 512 + (size_t)lane * 8;
    const short* Bb = Bw + ((size_t)((bh * 32 + bx * 4 + wn) * 4)) * 512 + (size_t)lane * 8;
    // next 32-tile: +2048 shorts; next ks: +512 shorts

    floatx16 acc[2][2];
    #pragma unroll
    for (int mi = 0; mi < 2; ++mi)
        #pragma unroll
        for (int ni = 0; ni < 2; ++ni)
            #pragma unroll
            for (int r = 0; r < 16; ++r)
                acc[mi][ni][r] = 0.0f;

    #pragma unroll
    for (int ks = 0; ks < 4; ++ks) {
        bf16x8 a0 = *(const bf16x8*)(Ab + ks * 512);
        bf16x8 a1 = *(const bf16x8*)(Ab + 2048 + ks * 512);
        bf16x8 b0 = *(const bf16x8*)(Bb + ks * 512);
        bf16x8 b1 = *(const bf16x8*)(Bb + 2048 + ks * 512);
        acc[0][0] = __builtin_amdgcn_mfma_f32_32x32x16_bf16(a0, b0, acc[0][0], 0, 0, 0);
        acc[0][1] = __builtin_amdgcn_mfma_f32_32x32x16_bf16(a0, b1, acc[0][1], 0, 0, 0);
        acc[1][0] = __builtin_amdgcn_mfma_f32_32x32x16_bf16(a1, b0, acc[1][0], 0, 0, 0);
        acc[1][1] = __builtin_amdgcn_mfma_f32_32x32x16_bf16(a1, b1, acc[1][1], 0, 0, 0);
    }

    const int nc    = lane & 31;        // n within 32-tile (contiguous across lanes)
    const int rbase = (lane >> 5) * 4;  // m sub-base
    float* Cb = C + ((size_t)bh << 20)
                  + (size_t)(by * 128 + wm * 32) * NN
                  + bx * 128 + wn * 32 + nc;

    #pragma unroll
    for (int mi = 0; mi < 2; ++mi) {
        #pragma unroll
        for (int ni = 0; ni < 2; ++ni) {
            float* Ct = Cb + (size_t)(mi * 32) * NN + ni * 32;
            #pragma unroll
            for (int r = 0; r < 16; ++r) {
                int row = rbase + (r & 3) + ((r >> 2) * 8);
                __builtin_nontemporal_store(acc[mi][ni][r], Ct + (size_t)row * NN);
            }
        }
    }
}

extern "C" void kernel_launch(void* const* d_in, const int* in_sizes, int n_in,
                              void* d_out, int out_size, void* d_ws, size_t ws_size,
                              hipStream_t stream) {
    const float* x1 = (const float*)d_in[0];   // [2,12,1024,64]
    const float* x2 = (const float*)d_in[1];   // [2,12,64,1024]
    float* out = (float*)d_out;                // [2,12,1024,1024] fp32

    short* Aw = (short*)d_ws;                  // 1,572,864 bf16 = 3.1 MB
    short* Bw = Aw + 1572864;                  // 3.1 MB

    hipLaunchKernelGGL(reformat_AB, dim3(384), dim3(256), 0, stream, x1, x2, Aw, Bw);
    hipLaunchKernelGGL(bmm_frag, dim3(8, 8, 24), dim3(256), 0, stream, Aw, Bw, out);
}